// Round 6
// baseline (297.733 us; speedup 1.0000x reference)
//
#include <hip/hip_runtime.h>
#include <stdint.h>

#define N_NODES_C 100000
#define N_EDGES_C 1600000
#define DIM 64
#define BN_EPS_C 1e-5f
#define BSH 7                      // 128 nodes per bucket
#define NB 782                     // ceil(100000 / 128)
#define CH 8192                    // edges per binscatter block
#define NT 7                       // source tiles of 16384 nodes (src>>14, max 6)
#define RPS 7                      // rows per half-wave slot

// ---------- index helper: supports int32 or int64 edge_index ----------
__device__ __forceinline__ int ld_idx(const void* p, int is64, size_t i) {
    if (is64) return (int)((const long long*)p)[i];
    return ((const int*)p)[i];
}

__device__ __forceinline__ float bflo(unsigned int u) {
    return __uint_as_float(u << 16);
}
__device__ __forceinline__ float bfhi(unsigned int u) {
    return __uint_as_float(u & 0xFFFF0000u);
}
__device__ __forceinline__ unsigned short f2bf(float f) {   // round-to-nearest-even
    unsigned int u = __float_as_uint(f);
    return (unsigned short)((u + 0x7FFF + ((u >> 16) & 1)) >> 16);
}

// Probe: if edge_index is int64, the high 32-bit word of every element is 0
__global__ void probe_kernel(const unsigned int* __restrict__ p, int* __restrict__ flag) {
    if (threadIdx.x == 0 && blockIdx.x == 0) {
        int is64 = 1;
        for (int i = 1; i < 64; i += 2) {
            if (p[i] != 0u) { is64 = 0; break; }
        }
        *flag = is64;
    }
}

// ---------- bucket histogram of targets ----------
__global__ __launch_bounds__(256) void hist_kernel(const void* __restrict__ ei,
                                                   const int* __restrict__ flag,
                                                   int* __restrict__ bucket_cnt) {
    __shared__ int hist[NB];
    for (int i = threadIdx.x; i < NB; i += 256) hist[i] = 0;
    __syncthreads();
    int is64 = *flag;
    int stride = gridDim.x * blockDim.x;
    for (int e = blockIdx.x * blockDim.x + threadIdx.x; e < N_EDGES_C; e += stride) {
        int tg = ld_idx(ei, is64, (size_t)N_EDGES_C + e);
        atomicAdd(&hist[tg >> BSH], 1);
    }
    __syncthreads();
    for (int i = threadIdx.x; i < NB; i += 256) {
        int c = hist[i];
        if (c) atomicAdd(&bucket_cnt[i], c);
    }
}

// ---------- single-block prefix sum over buckets ----------
__global__ __launch_bounds__(1024) void bucketscan_kernel(const int* __restrict__ bucket_cnt,
                                                          int* __restrict__ bucket_base,
                                                          int* __restrict__ bucket_cursor) {
    __shared__ int s[1024];
    int t = threadIdx.x;
    int v = (t < NB) ? bucket_cnt[t] : 0;
    s[t] = v;
    __syncthreads();
    for (int off = 1; off < 1024; off <<= 1) {
        int u = (t >= off) ? s[t - off] : 0;
        __syncthreads();
        s[t] += u;
        __syncthreads();
    }
    if (t < NB) {
        int excl = s[t] - v;
        bucket_base[t] = excl;
        bucket_cursor[t] = excl;
    }
}

// ---------- binned scatter: pack (tgt_local<<17 | src), locally grouped writes ----------
__global__ __launch_bounds__(256) void binscatter_kernel(const void* __restrict__ ei,
                                                         const int* __restrict__ flag,
                                                         int* __restrict__ bucket_cursor,
                                                         unsigned int* __restrict__ csr) {
    __shared__ int hist[NB];
    __shared__ int base[NB];
    int is64 = *flag;
    int e0 = blockIdx.x * CH;
    int eend = min(e0 + CH, N_EDGES_C);
    for (int i = threadIdx.x; i < NB; i += 256) hist[i] = 0;
    __syncthreads();
    for (int e = e0 + threadIdx.x; e < eend; e += 256) {
        int tg = ld_idx(ei, is64, (size_t)N_EDGES_C + e);
        atomicAdd(&hist[tg >> BSH], 1);
    }
    __syncthreads();
    for (int i = threadIdx.x; i < NB; i += 256) {
        int c = hist[i];
        base[i] = c ? atomicAdd(&bucket_cursor[i], c) : 0;
        hist[i] = 0;
    }
    __syncthreads();
    for (int e = e0 + threadIdx.x; e < eend; e += 256) {
        int s  = ld_idx(ei, is64, (size_t)e);
        int tg = ld_idx(ei, is64, (size_t)N_EDGES_C + e);
        int b  = tg >> BSH;
        int tl = tg & 127;
        int pos = base[b] + atomicAdd(&hist[b], 1);
        csr[pos] = ((unsigned int)tl << 17) | (unsigned int)s;
    }
}

// ---------- per-bucket counting sort by (tgt_local, src_tile) -> csr2 (src only);
// ---------- emits tilebase[node*8 + 0..7] (absolute csr2 offsets) and dinv ----------
__global__ __launch_bounds__(256) void sort_kernel(const unsigned int* __restrict__ csr,
                                                   const int* __restrict__ bucket_base,
                                                   const int* __restrict__ bucket_cnt,
                                                   int* __restrict__ csr2,
                                                   int* __restrict__ tilebase,
                                                   float* __restrict__ dinv) {
    __shared__ int cnt[128 * NT];
    __shared__ int sbase[128 * NT + 1];
    __shared__ int cur[128 * NT];
    int bk = blockIdx.x;
    int t = threadIdx.x;
    for (int i = t; i < 128 * NT; i += 256) cnt[i] = 0;
    __syncthreads();
    int base = bucket_base[bk], n = bucket_cnt[bk];
    for (int i = t; i < n; i += 256) {
        unsigned int v = csr[base + i];
        int key = (int)(v >> 17) * NT + (int)((v & 0x1FFFF) >> 14);
        atomicAdd(&cnt[key], 1);
    }
    __syncthreads();
    if (t == 0) {
        int run = 0;
        for (int k = 0; k < 128 * NT; ++k) { sbase[k] = run; run += cnt[k]; }
        sbase[128 * NT] = run;
    }
    __syncthreads();
    for (int i = t; i < 128 * NT; i += 256) cur[i] = base + sbase[i];
    if (t < 128) {
        int node = (bk << BSH) + t;
        if (node < N_NODES_C) {
#pragma unroll
            for (int k = 0; k < NT; ++k)
                tilebase[node * 8 + k] = base + sbase[t * NT + k];
            tilebase[node * 8 + NT] = base + sbase[t * NT + NT];
            int d = sbase[t * NT + NT] - sbase[t * NT];
            dinv[node] = rsqrtf((float)(d + 1));   // +1 self-loop
        }
    }
    __syncthreads();
    for (int i = t; i < n; i += 256) {
        unsigned int v = csr[base + i];
        int key = (int)(v >> 17) * NT + (int)((v & 0x1FFFF) >> 14);
        int pos = atomicAdd(&cur[key], 1);
        csr2[pos] = (int)(v & 0x1FFFF);
    }
}

// ---------- hs = (x @ W^T) * dinv[row]  -> bf16 ----------
__global__ __launch_bounds__(256) void gemm_kernel(const float* __restrict__ x,
                                                   const float* __restrict__ W,
                                                   const float* __restrict__ dinv,
                                                   unsigned short* __restrict__ hs) {
    __shared__ float Wl[DIM * 65];
    __shared__ float xs[32][DIM];
    int t = threadIdx.x;
    for (int i = t; i < DIM * DIM; i += 256) {
        Wl[(i >> 6) * 65 + (i & 63)] = W[i];
    }
    int r0 = blockIdx.x * 32;
    for (int i = t; i < 32 * DIM; i += 256) {
        int row = i >> 6, col = i & 63;
        int r = r0 + row;
        xs[row][col] = (r < N_NODES_C) ? x[(size_t)r * DIM + col] : 0.0f;
    }
    __syncthreads();
    int wv = t >> 6, c = t & 63;
    for (int it = 0; it < 8; ++it) {
        int rl = it * 4 + wv;
        int r = r0 + rl;
        float acc = 0.0f;
#pragma unroll
        for (int k = 0; k < DIM; ++k) acc += xs[rl][k] * Wl[c * 65 + k];
        if (r < N_NODES_C) hs[(size_t)r * DIM + c] = f2bf(acc * dinv[r]);
    }
}

// ---------- gather: tile-phased sweep. Half-wave slot owns RPS contiguous rows,
// f32 register accumulators; per tile, process each row's tile segment.
// out[t] = (sum_src hs[src] + hs[t]) * dinv[t] + b ; fused BN stats ----------
__global__ __launch_bounds__(256) void gather_kernel(const int* __restrict__ csr2,
                                                     const int* __restrict__ tilebase,
                                                     const float* __restrict__ dinv,
                                                     const unsigned int* __restrict__ hs2,
                                                     const float* __restrict__ b_,
                                                     float2* __restrict__ out,
                                                     float* __restrict__ sums,
                                                     float* __restrict__ sumsq) {
    int lane = threadIdx.x & 63;
    int half = lane >> 5;
    int c2 = lane & 31;
    int slot = (blockIdx.x * 4 + (threadIdx.x >> 6)) * 2 + half;
    int row0 = slot * RPS;
    float a0[RPS], a1[RPS];
#pragma unroll
    for (int r = 0; r < RPS; ++r) { a0[r] = 0.0f; a1[r] = 0.0f; }

    for (int tt = 0; tt < NT; ++tt) {
        int sr[RPS], er[RPS];
#pragma unroll
        for (int r = 0; r < RPS; ++r) {
            int node = row0 + r;
            bool valid = node < N_NODES_C;
            sr[r] = valid ? tilebase[node * 8 + tt] : 0;
            er[r] = valid ? tilebase[node * 8 + tt + 1] : 0;
        }
#pragma unroll
        for (int r = 0; r < RPS; ++r) {
            float x0 = a0[r], x1 = a1[r];
            int j = sr[r], e = er[r];
            for (; j + 4 <= e; j += 4) {
                int sA = csr2[j + 0];
                int sB = csr2[j + 1];
                int sC = csr2[j + 2];
                int sD = csr2[j + 3];
                unsigned int uA = hs2[(size_t)sA * 32 + c2];
                unsigned int uB = hs2[(size_t)sB * 32 + c2];
                unsigned int uC = hs2[(size_t)sC * 32 + c2];
                unsigned int uD = hs2[(size_t)sD * 32 + c2];
                x0 += bflo(uA); x1 += bfhi(uA);
                x0 += bflo(uB); x1 += bfhi(uB);
                x0 += bflo(uC); x1 += bfhi(uC);
                x0 += bflo(uD); x1 += bfhi(uD);
            }
            for (; j < e; ++j) {
                int s = csr2[j];
                unsigned int u = hs2[(size_t)s * 32 + c2];
                x0 += bflo(u); x1 += bfhi(u);
            }
            a0[r] = x0; a1[r] = x1;
        }
    }

    float2 bb = ((const float2*)b_)[c2];
    float s0a = 0.0f, q0a = 0.0f, s1a = 0.0f, q1a = 0.0f;
#pragma unroll
    for (int r = 0; r < RPS; ++r) {
        int node = row0 + r;
        if (node < N_NODES_C) {
            unsigned int ut = hs2[(size_t)node * 32 + c2];
            float dt = dinv[node];
            float v0 = fmaf(a0[r] + bflo(ut), dt, bb.x);
            float v1 = fmaf(a1[r] + bfhi(ut), dt, bb.y);
            out[(size_t)node * 32 + c2] = make_float2(v0, v1);
            s0a += v0; q0a += v0 * v0;
            s1a += v1; q1a += v1 * v1;
        }
    }
    __shared__ float r0[256], r1[256], r2[256], r3[256];
    r0[threadIdx.x] = s0a; r1[threadIdx.x] = q0a;
    r2[threadIdx.x] = s1a; r3[threadIdx.x] = q1a;
    __syncthreads();
    if (threadIdx.x < 32) {
        float S0 = 0, Q0 = 0, S1 = 0, Q1 = 0;
        for (int k = threadIdx.x; k < 256; k += 32) {
            S0 += r0[k]; Q0 += r1[k]; S1 += r2[k]; Q1 += r3[k];
        }
        unsafeAtomicAdd(&sums[2 * threadIdx.x], S0);
        unsafeAtomicAdd(&sums[2 * threadIdx.x + 1], S1);
        unsafeAtomicAdd(&sumsq[2 * threadIdx.x], Q0);
        unsafeAtomicAdd(&sumsq[2 * threadIdx.x + 1], Q1);
    }
}

__global__ void bnparam_kernel(const float* __restrict__ sums,
                               const float* __restrict__ sumsq,
                               const float* __restrict__ gamma,
                               const float* __restrict__ beta,
                               float* __restrict__ scale,
                               float* __restrict__ shift) {
    int c = threadIdx.x;
    if (c < DIM) {
        float m = sums[c] * (1.0f / N_NODES_C);
        float var = sumsq[c] * (1.0f / N_NODES_C) - m * m;
        float sc = gamma[c] * rsqrtf(var + BN_EPS_C);
        scale[c] = sc;
        shift[c] = beta[c] - m * sc;
    }
}

__global__ __launch_bounds__(256) void bnrelu_kernel(float4* __restrict__ out,
                                                     const float* __restrict__ scale,
                                                     const float* __restrict__ shift) {
    const int n4 = N_NODES_C * (DIM / 4);
    int stride = gridDim.x * blockDim.x;
    for (int i = blockIdx.x * blockDim.x + threadIdx.x; i < n4; i += stride) {
        int cb = (i & 15) * 4;
        float4 v = out[i];
        v.x = fmaxf(fmaf(v.x, scale[cb + 0], shift[cb + 0]), 0.0f);
        v.y = fmaxf(fmaf(v.y, scale[cb + 1], shift[cb + 1]), 0.0f);
        v.z = fmaxf(fmaf(v.z, scale[cb + 2], shift[cb + 2]), 0.0f);
        v.w = fmaxf(fmaf(v.w, scale[cb + 3], shift[cb + 3]), 0.0f);
        out[i] = v;
    }
}

extern "C" void kernel_launch(void* const* d_in, const int* in_sizes, int n_in,
                              void* d_out, int out_size, void* d_ws, size_t ws_size,
                              hipStream_t stream) {
    const float* x     = (const float*)d_in[0];
    const void*  ei    = d_in[1];
    const float* W     = (const float*)d_in[2];
    const float* b     = (const float*)d_in[3];
    const float* gamma = (const float*)d_in[4];
    const float* beta  = (const float*)d_in[5];
    float* out = (float*)d_out;

    char* ws = (char*)d_ws;
    int*   flag          = (int*)(ws + 0);
    int*   bucket_cnt    = (int*)(ws + 256);       // 3328 B
    int*   bucket_base   = (int*)(ws + 3584);      // 3328 B
    int*   bucket_cursor = (int*)(ws + 6912);      // 3328 B
    float* dinv          = (float*)(ws + 10240);   // 400000 B
    int*   tilebase      = (int*)(ws + 410240);    // 3,200,000 B
    float* sums          = (float*)(ws + 3610240); // 256 B
    float* sumsq         = (float*)(ws + 3610496); // 256 B
    float* scale         = (float*)(ws + 3610752); // 256 B
    float* shift         = (float*)(ws + 3611008); // 256 B
    int*   csr2          = (int*)(ws + 3611264);            // 6,400,000 B
    unsigned int* csr    = (unsigned int*)(ws + 10011264);  // 6,400,000 B (dead after sort)
    unsigned short* hs   = (unsigned short*)(ws + 10011264); // 12,800,000 B (overlays csr)

    hipMemsetAsync(bucket_cnt, 0, NB * sizeof(int), stream);
    hipMemsetAsync(sums, 0, 512, stream);  // sums + sumsq contiguous

    probe_kernel<<<1, 64, 0, stream>>>((const unsigned int*)ei, flag);
    hist_kernel<<<256, 256, 0, stream>>>(ei, flag, bucket_cnt);
    bucketscan_kernel<<<1, 1024, 0, stream>>>(bucket_cnt, bucket_base, bucket_cursor);
    binscatter_kernel<<<(N_EDGES_C + CH - 1) / CH, 256, 0, stream>>>(ei, flag,
                                                                    bucket_cursor, csr);
    sort_kernel<<<NB, 256, 0, stream>>>(csr, bucket_base, bucket_cnt, csr2,
                                        tilebase, dinv);
    gemm_kernel<<<(N_NODES_C + 31) / 32, 256, 0, stream>>>(x, W, dinv, hs);
    gather_kernel<<<2048, 256, 0, stream>>>(csr2, tilebase, dinv,
                                            (const unsigned int*)hs, b,
                                            (float2*)out, sums, sumsq);
    bnparam_kernel<<<1, 64, 0, stream>>>(sums, sumsq, gamma, beta, scale, shift);
    bnrelu_kernel<<<1024, 256, 0, stream>>>((float4*)out, scale, shift);
}